// Round 8
// baseline (589.797 us; speedup 1.0000x reference)
//
#include <hip/hip_runtime.h>

// Problem constants (QLinear_17918603559229)
#define TOKENS 8192
#define IN_F   4096
#define OUT_F  4096
#define GK     IN_F
#define GN     OUT_F

#define BM 128
#define BN 64
#define BK 64

typedef __attribute__((ext_vector_type(8))) short bf16x8;
typedef __attribute__((ext_vector_type(4))) float f32x4;
typedef __attribute__((address_space(1))) void gvoid;
typedef __attribute__((address_space(3))) void lvoid;

static __device__ __forceinline__ unsigned short f32_to_bf16(float f) {
  union { float f; unsigned int u; } v; v.f = f;
  unsigned int u = v.u;
  return (unsigned short)((u + 0x7FFFu + ((u >> 16) & 1u)) >> 16);  // RNE
}

// ---------------- fused prep: cast x (f32->bf16) + build W (bf16) ----------------
// blocks [0, 16384): cast 8 elems/thread; blocks [16384, 32768): build 4 elems/thread
__global__ void prep_kernel(const float4* __restrict__ x, bf16x8* __restrict__ xb,
                            const float* __restrict__ a, const float* __restrict__ s,
                            unsigned short* __restrict__ wb) {
  const int bid = blockIdx.x;
  if (bid < 16384) {
    const int idx = bid * 256 + threadIdx.x;
    float4 v0 = x[idx * 2];
    float4 v1 = x[idx * 2 + 1];
    bf16x8 r;
    r[0] = (short)f32_to_bf16(v0.x); r[1] = (short)f32_to_bf16(v0.y);
    r[2] = (short)f32_to_bf16(v0.z); r[3] = (short)f32_to_bf16(v0.w);
    r[4] = (short)f32_to_bf16(v1.x); r[5] = (short)f32_to_bf16(v1.y);
    r[6] = (short)f32_to_bf16(v1.z); r[7] = (short)f32_to_bf16(v1.w);
    xb[idx] = r;
  } else {
    const int gid = (bid - 16384) * 256 + threadIdx.x;   // OUT_F * IN_F / 4 threads
    const int o = gid >> 10;
    const int i = (gid & 1023) << 2;                      // 4 consecutive i, same j-block
    const int ib = o >> 10, p = o & 1023;
    const int jb = i >> 10, q = i & 1023;
    float r0 = 0.f, r1 = 0.f, r2 = 0.f, r3 = 0.f;
#pragma unroll
    for (int k = 0; k < 4; ++k) {
      float ak = a[k * 16 + ib * 4 + jb];
      const float4 sv = *(const float4*)(s + (((size_t)(k * 1024 + p)) << 10) + q);
      r0 += ak * sv.x; r1 += ak * sv.y; r2 += ak * sv.z; r3 += ak * sv.w;
    }
    ushort4 w;
    w.x = f32_to_bf16(r0); w.y = f32_to_bf16(r1);
    w.z = f32_to_bf16(r2); w.w = f32_to_bf16(r3);
    *(ushort4*)(wb + ((size_t)o << 12) + i) = w;
  }
}

// ---------------- GEMM: C[M,N] = A[M,K] @ B[N,K]^T + bias, bf16 in / f32 out ----------------
// Evidence ladder (this problem, this chip):
//   r0/r4/r6: 128x128, 4 waves, 2-barrier loop: 245 us, MfmaUtil 55%, 12 waves/CU, 3 blocks/CU
//   r5:       128x128, 2 waves (64x128/wave):   297 us, MfmaUtil 42%  (occupancy collapse)
//   r2/r3:    256x256, 8 waves, 8-phase port:   335+ us, MfmaUtil 34% (1 block/CU, no slip)
//   r6:       launch_bounds(256,4) reg squeeze: neutral — occupancy cap is NOT registers
//   => perf tracks INDEPENDENT BLOCKS per CU (barrier-drain slip), not FLOP/LDS-byte.
// This round (retry of r7 — infra flake, kernel audited clean): 128x64 tile, TWO waves
// (each 64x64 — identical per-wave work/regs/LDS-ratio to the proven r0 kernel), LDS
// 24 KB -> 6 blocks/CU (LDS-capped) = same 12 waves/CU but 6 independent barrier groups
// instead of 3, and narrower (2-wave) barriers.
// Swizzle unchanged: LDS[row][g] = G[row][g ^ (row&7)], inverse-swizzle on global source,
// lane-contiguous LDS dest (global_load_lds requirement), swizzled ds_read column.
__global__ __launch_bounds__(128, 3)
void gemm_bias_kernel(const unsigned short* __restrict__ A,
                      const unsigned short* __restrict__ B,
                      const float* __restrict__ bias,
                      float* __restrict__ C) {
  __shared__ unsigned short As[BM * BK];   // 16 KB
  __shared__ unsigned short Bs[BN * BK];   // 8 KB   (24 KB total -> 6 blocks/CU)

  const int tid  = threadIdx.x;
  const int lane = tid & 63;
  const int wave = tid >> 6;               // 0..1
  const int m0 = blockIdx.y * BM;
  const int n0 = blockIdx.x * BN;
  const int wm = wave * 64;                // wave's M slab; both waves span all 64 cols

  f32x4 acc[4][4];
#pragma unroll
  for (int mi = 0; mi < 4; ++mi)
#pragma unroll
    for (int ni = 0; ni < 4; ++ni)
      acc[mi][ni] = (f32x4){0.f, 0.f, 0.f, 0.f};

  // staging map: pass p covers rows p*16 + (tid>>3); granule (tid&7), swizzled source
  const int srow = tid >> 3;               // 0..15
  const int sgr  = (tid & 7) ^ (srow & 7);
  const unsigned short* Ag = A + (size_t)(m0 + srow) * GK + sgr * 8;
  const unsigned short* Bg = B + (size_t)(n0 + srow) * GK + sgr * 8;
  unsigned short* Asd = As + tid * 8;      // lane-contiguous LDS dest
  unsigned short* Bsd = Bs + tid * 8;

  const int ln15 = lane & 15;
  const int quad = lane >> 4;
  const int sw   = lane & 7;               // == (frag row) & 7
  int rowA[4], rowB[4];
#pragma unroll
  for (int t = 0; t < 4; ++t) {
    rowA[t] = (wm + t * 16 + ln15) * BK;
    rowB[t] = (t * 16 + ln15) * BK;
  }

  for (int k0 = 0; k0 < GK; k0 += BK) {
#pragma unroll
    for (int p = 0; p < 8; ++p)
      __builtin_amdgcn_global_load_lds((const gvoid*)(Ag + (size_t)(p * 16) * GK + k0),
                                       (lvoid*)(Asd + p * 1024), 16, 0, 0);
#pragma unroll
    for (int p = 0; p < 4; ++p)
      __builtin_amdgcn_global_load_lds((const gvoid*)(Bg + (size_t)(p * 16) * GK + k0),
                                       (lvoid*)(Bsd + p * 1024), 16, 0, 0);
    __syncthreads();
#pragma unroll
    for (int half = 0; half < 2; ++half) {
      const int gk   = half * 4 + quad;          // source granule wanted (k = gk*8 + j)
      const int cofs = ((gk ^ sw) << 3);         // swizzled LDS column (elements)
      bf16x8 af[4], bfr[4];
#pragma unroll
      for (int t = 0; t < 4; ++t) {
        af[t]  = *(const bf16x8*)(As + rowA[t] + cofs);
        bfr[t] = *(const bf16x8*)(Bs + rowB[t] + cofs);
      }
#pragma unroll
      for (int mi = 0; mi < 4; ++mi)
#pragma unroll
        for (int ni = 0; ni < 4; ++ni)
          acc[mi][ni] = __builtin_amdgcn_mfma_f32_16x16x32_bf16(af[mi], bfr[ni],
                                                                acc[mi][ni], 0, 0, 0);
    }
    __syncthreads();
  }

  // epilogue: C/D layout col = lane&15, row = quad*4 + reg  [m89/m91 verified]
#pragma unroll
  for (int ni = 0; ni < 4; ++ni) {
    const int col = n0 + ni * 16 + ln15;
    const float bv = bias[col];
#pragma unroll
    for (int mi = 0; mi < 4; ++mi) {
      const int rowb = m0 + wm + mi * 16 + quad * 4;
#pragma unroll
      for (int r = 0; r < 4; ++r)
        C[(size_t)(rowb + r) * GN + col] = acc[mi][ni][r] + bv;
    }
  }
}

// ---------------- naive fallback (only if ws too small) ----------------
__global__ void naive_kernel(const float* __restrict__ x, const float* __restrict__ a,
                             const float* __restrict__ s, const float* __restrict__ bias,
                             float* __restrict__ out) {
  long long idx = (long long)blockIdx.x * blockDim.x + threadIdx.x;
  if (idx >= (long long)TOKENS * OUT_F) return;
  int t = (int)(idx >> 12);
  int o = (int)(idx & 4095);
  int ib = o >> 10, p = o & 1023;
  float acc = bias[o];
  for (int jb = 0; jb < 4; ++jb) {
    float a0 = a[0  + ib * 4 + jb];
    float a1 = a[16 + ib * 4 + jb];
    float a2 = a[32 + ib * 4 + jb];
    float a3 = a[48 + ib * 4 + jb];
    const float* xr = x + (size_t)t * IN_F + jb * 1024;
    const float* s0 = s + (size_t)p * 1024;
    const float* s1 = s0 + 1048576;
    const float* s2 = s1 + 1048576;
    const float* s3 = s2 + 1048576;
    for (int q = 0; q < 1024; ++q) {
      float w = a0 * s0[q] + a1 * s1[q] + a2 * s2[q] + a3 * s3[q];
      acc += xr[q] * w;
    }
  }
  out[idx] = acc;
}

extern "C" void kernel_launch(void* const* d_in, const int* in_sizes, int n_in,
                              void* d_out, int out_size, void* d_ws, size_t ws_size,
                              hipStream_t stream) {
  const float* x    = (const float*)d_in[0];
  const float* a    = (const float*)d_in[1];
  const float* s    = (const float*)d_in[2];
  const float* bias = (const float*)d_in[3];
  float* out = (float*)d_out;

  const size_t xb_elems = (size_t)TOKENS * IN_F;          // 33.5M bf16 = 67 MB
  const size_t wb_elems = (size_t)OUT_F * IN_F;           // 16.7M bf16 = 33.5 MB
  const size_t need = (xb_elems + wb_elems) * sizeof(unsigned short);

  if (ws_size >= need) {
    unsigned short* Xb = (unsigned short*)d_ws;
    unsigned short* Wb = Xb + xb_elems;
    const int cast_blocks  = (int)(xb_elems / 8 / 256);   // 16384
    const int build_blocks = (int)(wb_elems / 4 / 256);   // 16384
    prep_kernel<<<cast_blocks + build_blocks, 256, 0, stream>>>(
        (const float4*)x, (bf16x8*)Xb, a, s, Wb);
    dim3 grid(GN / BN, TOKENS / BM);                      // (64, 64) = 4096 blocks
    gemm_bias_kernel<<<grid, 128, 0, stream>>>(Xb, Wb, bias, out);
  } else {
    long long total = (long long)TOKENS * OUT_F;
    naive_kernel<<<(int)((total + 255) / 256), 256, 0, stream>>>(x, a, s, bias, out);
  }
}

// Round 9
// 496.247 us; speedup vs baseline: 1.1885x; 1.1885x over previous
//
#include <hip/hip_runtime.h>

// Problem constants (QLinear_17918603559229)
#define TOKENS 8192
#define IN_F   4096
#define OUT_F  4096
#define GK     IN_F
#define GN     OUT_F

#define BM 128
#define BN 128
#define BK 64

typedef __attribute__((ext_vector_type(8))) short bf16x8;
typedef __attribute__((ext_vector_type(4))) float f32x4;
typedef __attribute__((address_space(1))) void gvoid;
typedef __attribute__((address_space(3))) void lvoid;

static __device__ __forceinline__ unsigned short f32_to_bf16(float f) {
  union { float f; unsigned int u; } v; v.f = f;
  unsigned int u = v.u;
  return (unsigned short)((u + 0x7FFFu + ((u >> 16) & 1u)) >> 16);  // RNE
}

// ---------------- fused prep: cast x (f32->bf16) + build W (bf16) ----------------
// blocks [0, 16384): cast 8 elems/thread; blocks [16384, 32768): build 4 elems/thread
__global__ void prep_kernel(const float4* __restrict__ x, bf16x8* __restrict__ xb,
                            const float* __restrict__ a, const float* __restrict__ s,
                            unsigned short* __restrict__ wb) {
  const int bid = blockIdx.x;
  if (bid < 16384) {
    const int idx = bid * 256 + threadIdx.x;
    float4 v0 = x[idx * 2];
    float4 v1 = x[idx * 2 + 1];
    bf16x8 r;
    r[0] = (short)f32_to_bf16(v0.x); r[1] = (short)f32_to_bf16(v0.y);
    r[2] = (short)f32_to_bf16(v0.z); r[3] = (short)f32_to_bf16(v0.w);
    r[4] = (short)f32_to_bf16(v1.x); r[5] = (short)f32_to_bf16(v1.y);
    r[6] = (short)f32_to_bf16(v1.z); r[7] = (short)f32_to_bf16(v1.w);
    xb[idx] = r;
  } else {
    const int gid = (bid - 16384) * 256 + threadIdx.x;   // OUT_F * IN_F / 4 threads
    const int o = gid >> 10;
    const int i = (gid & 1023) << 2;                      // 4 consecutive i, same j-block
    const int ib = o >> 10, p = o & 1023;
    const int jb = i >> 10, q = i & 1023;
    float r0 = 0.f, r1 = 0.f, r2 = 0.f, r3 = 0.f;
#pragma unroll
    for (int k = 0; k < 4; ++k) {
      float ak = a[k * 16 + ib * 4 + jb];
      const float4 sv = *(const float4*)(s + (((size_t)(k * 1024 + p)) << 10) + q);
      r0 += ak * sv.x; r1 += ak * sv.y; r2 += ak * sv.z; r3 += ak * sv.w;
    }
    ushort4 w;
    w.x = f32_to_bf16(r0); w.y = f32_to_bf16(r1);
    w.z = f32_to_bf16(r2); w.w = f32_to_bf16(r3);
    *(ushort4*)(wb + ((size_t)o << 12) + i) = w;
  }
}

// ---------------- GEMM: C[M,N] = A[M,K] @ B[N,K]^T + bias, bf16 in / f32 out ----------------
// Evidence ladder (this problem, this chip):
//   r0/r4/r6: THIS kernel (no swizzle): 245-257 us, MfmaUtil 55%, 3 blocks/CU — family best
//   r5: 2-wave 64x128/wave: 297 us, 42% | r2/r3: 256^2 8-phase ports: 335-369 us, 30-34%
//   r6: launch_bounds reg squeeze: neutral | r8: 128x64 6-blk/CU: 340 us, 36%, FETCH 825 MB
//   => occupancy/geometry levers exhausted; structure optimum is 128^2/4-wave/3-blk.
// Remaining measured anomaly: FETCH 390 MB vs ~100 MB operand footprint (4x L2-miss
// overfetch). Default dispatch order: consecutive ids share an A-panel but sweep all 32
// B-panels -> ~35 MB concurrent window vs 4 MB per-XCD L2 -> every K-step's
// global_load_lds batch misses L2, and the syncthreads vmcnt-drain waits LLC latency.
// THIS ROUND (T1, bijective): XCD-chunked + 2D-supertiled blockIdx remap.
//   g = y*32+x; xcd = g&7 (HW round-robin, m09); slot = g>>3;
//   mrow = xcd*8 + (slot&7)  [each XCD owns an 8-M-row band]
//   ncol = slot>>3           [8 consecutive slots share one B-panel]
// Bijective: (xcd,slot) <-> (mrow,ncol) covers 64x32 exactly once.
// Swizzle unchanged: LDS[row][g] = G[row][g ^ (row&7)], inverse-swizzle on global src,
// lane-contiguous LDS dest (global_load_lds requirement), swizzled ds_read column.
__global__ __launch_bounds__(256, 2)
void gemm_bias_kernel(const unsigned short* __restrict__ A,
                      const unsigned short* __restrict__ B,
                      const float* __restrict__ bias,
                      float* __restrict__ C) {
  __shared__ unsigned short As[BM * BK];   // 16 KB
  __shared__ unsigned short Bs[BN * BK];   // 16 KB

  const int tid  = threadIdx.x;
  const int lane = tid & 63;
  const int wave = tid >> 6;

  // XCD-aware bijective remap (see header comment)
  const int g    = blockIdx.y * gridDim.x + blockIdx.x;  // 0..2047
  const int xcd  = g & 7;
  const int slot = g >> 3;                                // 0..255
  const int ncol = slot >> 3;                             // 0..31
  const int mrow = (xcd << 3) | (slot & 7);               // 0..63
  const int m0 = mrow * BM;
  const int n0 = ncol * BN;

  const int wm = (wave >> 1) * 64;
  const int wn = (wave & 1) * 64;

  f32x4 acc[4][4];
#pragma unroll
  for (int mi = 0; mi < 4; ++mi)
#pragma unroll
    for (int ni = 0; ni < 4; ++ni)
      acc[mi][ni] = (f32x4){0.f, 0.f, 0.f, 0.f};

  // staging map: pass p covers rows p*32 + (tid>>3); granule (tid&7), swizzled source
  const int srow = tid >> 3;
  const int sgr  = (tid & 7) ^ (srow & 7);
  const unsigned short* Ag = A + (size_t)(m0 + srow) * GK + sgr * 8;
  const unsigned short* Bg = B + (size_t)(n0 + srow) * GK + sgr * 8;
  unsigned short* Asd = As + tid * 8;      // lane-contiguous LDS dest
  unsigned short* Bsd = Bs + tid * 8;

  const int ln15 = lane & 15;
  const int quad = lane >> 4;
  const int sw   = lane & 7;               // == (frag row) & 7
  int rowA[4], rowB[4];
#pragma unroll
  for (int t = 0; t < 4; ++t) {
    rowA[t] = (wm + t * 16 + ln15) * BK;
    rowB[t] = (wn + t * 16 + ln15) * BK;
  }

  for (int k0 = 0; k0 < GK; k0 += BK) {
#pragma unroll
    for (int p = 0; p < 4; ++p) {
      __builtin_amdgcn_global_load_lds((const gvoid*)(Ag + (size_t)(p * 32) * GK + k0),
                                       (lvoid*)(Asd + p * 2048), 16, 0, 0);
      __builtin_amdgcn_global_load_lds((const gvoid*)(Bg + (size_t)(p * 32) * GK + k0),
                                       (lvoid*)(Bsd + p * 2048), 16, 0, 0);
    }
    __syncthreads();
#pragma unroll
    for (int half = 0; half < 2; ++half) {
      const int gk   = half * 4 + quad;          // source granule wanted (k = gk*8 + j)
      const int cofs = ((gk ^ sw) << 3);         // swizzled LDS column (elements)
      bf16x8 af[4], bfr[4];
#pragma unroll
      for (int t = 0; t < 4; ++t) {
        af[t]  = *(const bf16x8*)(As + rowA[t] + cofs);
        bfr[t] = *(const bf16x8*)(Bs + rowB[t] + cofs);
      }
#pragma unroll
      for (int mi = 0; mi < 4; ++mi)
#pragma unroll
        for (int ni = 0; ni < 4; ++ni)
          acc[mi][ni] = __builtin_amdgcn_mfma_f32_16x16x32_bf16(af[mi], bfr[ni],
                                                                acc[mi][ni], 0, 0, 0);
    }
    __syncthreads();
  }

  // epilogue: C/D layout col = lane&15, row = quad*4 + reg  [m89/m91 verified]
#pragma unroll
  for (int ni = 0; ni < 4; ++ni) {
    const int col = n0 + wn + ni * 16 + ln15;
    const float bv = bias[col];
#pragma unroll
    for (int mi = 0; mi < 4; ++mi) {
      const int rowb = m0 + wm + mi * 16 + quad * 4;
#pragma unroll
      for (int r = 0; r < 4; ++r)
        C[(size_t)(rowb + r) * GN + col] = acc[mi][ni][r] + bv;
    }
  }
}

// ---------------- naive fallback (only if ws too small) ----------------
__global__ void naive_kernel(const float* __restrict__ x, const float* __restrict__ a,
                             const float* __restrict__ s, const float* __restrict__ bias,
                             float* __restrict__ out) {
  long long idx = (long long)blockIdx.x * blockDim.x + threadIdx.x;
  if (idx >= (long long)TOKENS * OUT_F) return;
  int t = (int)(idx >> 12);
  int o = (int)(idx & 4095);
  int ib = o >> 10, p = o & 1023;
  float acc = bias[o];
  for (int jb = 0; jb < 4; ++jb) {
    float a0 = a[0  + ib * 4 + jb];
    float a1 = a[16 + ib * 4 + jb];
    float a2 = a[32 + ib * 4 + jb];
    float a3 = a[48 + ib * 4 + jb];
    const float* xr = x + (size_t)t * IN_F + jb * 1024;
    const float* s0 = s + (size_t)p * 1024;
    const float* s1 = s0 + 1048576;
    const float* s2 = s1 + 1048576;
    const float* s3 = s2 + 1048576;
    for (int q = 0; q < 1024; ++q) {
      float w = a0 * s0[q] + a1 * s1[q] + a2 * s2[q] + a3 * s3[q];
      acc += xr[q] * w;
    }
  }
  out[idx] = acc;
}

extern "C" void kernel_launch(void* const* d_in, const int* in_sizes, int n_in,
                              void* d_out, int out_size, void* d_ws, size_t ws_size,
                              hipStream_t stream) {
  const float* x    = (const float*)d_in[0];
  const float* a    = (const float*)d_in[1];
  const float* s    = (const float*)d_in[2];
  const float* bias = (const float*)d_in[3];
  float* out = (float*)d_out;

  const size_t xb_elems = (size_t)TOKENS * IN_F;          // 33.5M bf16 = 67 MB
  const size_t wb_elems = (size_t)OUT_F * IN_F;           // 16.7M bf16 = 33.5 MB
  const size_t need = (xb_elems + wb_elems) * sizeof(unsigned short);

  if (ws_size >= need) {
    unsigned short* Xb = (unsigned short*)d_ws;
    unsigned short* Wb = Xb + xb_elems;
    const int cast_blocks  = (int)(xb_elems / 8 / 256);   // 16384
    const int build_blocks = (int)(wb_elems / 4 / 256);   // 16384
    prep_kernel<<<cast_blocks + build_blocks, 256, 0, stream>>>(
        (const float4*)x, (bf16x8*)Xb, a, s, Wb);
    dim3 grid(GN / BN, TOKENS / BM);                      // (32, 64) = 2048 blocks
    gemm_bias_kernel<<<grid, 256, 0, stream>>>(Xb, Wb, bias, out);
  } else {
    long long total = (long long)TOKENS * OUT_F;
    naive_kernel<<<(int)((total + 255) / 256), 256, 0, stream>>>(x, a, s, bias, out);
  }
}